// Round 15
// baseline (196.308 us; speedup 1.0000x reference)
//
#include <hip/hip_runtime.h>
#include <hip/hip_bf16.h>
#include <math.h>

#define N_NODES 50000
#define N_EDGES 600000
#define N_GRAPHS 512
#define DIM 128
#define OUTD 64
#define EPSV 1e-6f
#define BSTRIDE 64     // bucket slots per node; mean deg 12, P(deg>64) ~ 0
#define EBLK 2344      // ceil(N_EDGES/256)

typedef __attribute__((ext_vector_type(8))) short bf16x8;
typedef __attribute__((ext_vector_type(4))) float f32x4;

__device__ __forceinline__ float sgn(float v) {
    return (v > 0.f) ? 1.f : ((v < 0.f) ? -1.f : 0.f);
}

__device__ __forceinline__ float cube_signed(float v) {
    float m = fabsf(v) + EPSV;
    return sgn(v) * m * m * m;
}

__device__ __forceinline__ float cbrt_pos(float m) {
    return exp2f(log2f(m) * (1.0f / 3.0f));
}

__device__ __forceinline__ unsigned short f2bf(float f) {
    unsigned u = __float_as_uint(f);
    unsigned r = (u + 0x7fff + ((u >> 16) & 1)) >> 16;   // RNE
    return (unsigned short)r;
}

__device__ __forceinline__ float bf2f(unsigned short h) {
    return __uint_as_float(((unsigned)h) << 16);
}

// Wide gather (R10-proven pattern): lane&15 = feature octet, lane>>4 = edge
// slot. One uint4 load = 4 edges x 256B. Out-of-range slots masked ONCE at
// bucket load (idx 0 = dummy zero row of T) -> no csr memset needed.
__device__ __forceinline__ void gather_acc8(const unsigned* __restrict__ T32,
                                            const unsigned short* __restrict__ bucket,
                                            int cnt, int lane, float2 acc[4]) {
    #pragma unroll
    for (int j = 0; j < 4; j++) acc[j] = make_float2(0.f, 0.f);
    if (cnt <= 0) return;
    int myidx = (lane < cnt) ? (int)bucket[lane] : 0;   // coalesced 128B
    int sub = lane & 15, grp = lane >> 4;
    int cnt16 = (cnt + 15) & ~15;
    for (int i = 0; i < cnt16; i += 16) {
        uint4 u[4];
        #pragma unroll
        for (int c = 0; c < 4; c++) {
            int s = __shfl(myidx, i + c * 4 + grp, 64);
            u[c] = *(const uint4*)(T32 + (size_t)s * 64 + sub * 4);
        }
        #pragma unroll
        for (int c = 0; c < 4; c++) {
            acc[0].x += __uint_as_float(u[c].x << 16);
            acc[0].y += __uint_as_float(u[c].x & 0xffff0000u);
            acc[1].x += __uint_as_float(u[c].y << 16);
            acc[1].y += __uint_as_float(u[c].y & 0xffff0000u);
            acc[2].x += __uint_as_float(u[c].z << 16);
            acc[2].y += __uint_as_float(u[c].z & 0xffff0000u);
            acc[3].x += __uint_as_float(u[c].w << 16);
            acc[3].y += __uint_as_float(u[c].w & 0xffff0000u);
        }
    }
    #pragma unroll
    for (int j = 0; j < 4; j++) {
        acc[j].x += __shfl_xor(acc[j].x, 16, 64);
        acc[j].y += __shfl_xor(acc[j].y, 16, 64);
        acc[j].x += __shfl_xor(acc[j].x, 32, 64);
        acc[j].y += __shfl_xor(acc[j].y, 32, 64);
    }
}

__device__ __forceinline__ float acc_pick_x(const float2 acc[4], int grp) {
    return grp == 0 ? acc[0].x : grp == 1 ? acc[1].x : grp == 2 ? acc[2].x : acc[3].x;
}
__device__ __forceinline__ float acc_pick_y(const float2 acc[4], int grp) {
    return grp == 0 ? acc[0].y : grp == 1 ? acc[1].y : grp == 2 ? acc[2].y : acc[3].y;
}

// ---- prep: W1/W2 hi-lo split, gstart, T zero rows, deg zero ----------------

__global__ void prep(const float* __restrict__ W1, const float* __restrict__ W2,
                     unsigned short* __restrict__ W1hi, unsigned short* __restrict__ W1lo,
                     unsigned short* __restrict__ W2hi, unsigned short* __restrict__ W2lo,
                     int* __restrict__ deg,
                     const int* __restrict__ batch, int* __restrict__ gstart,
                     unsigned* __restrict__ T1z, unsigned* __restrict__ T2z) {
    int i = blockIdx.x * 256 + threadIdx.x;
    {
        float w = W1[i];
        unsigned short h = f2bf(w);
        W1hi[i] = h;
        W1lo[i] = f2bf(w - bf2f(h));
        w = W2[i];
        h = f2bf(w);
        W2hi[i] = h;
        W2lo[i] = f2bf(w - bf2f(h));
    }
    if (i < 64) { T1z[i] = 0u; T2z[i] = 0u; }   // dummy zero row 0
    if (i <= N_GRAPHS) {
        int lo = 0, hi = N_NODES;
        while (lo < hi) {
            int mid = (lo + hi) >> 1;
            if (batch[mid] < i) lo = mid + 1; else hi = mid;
        }
        gstart[i] = lo;
    }
    for (int j = i; j < N_NODES; j += 16384) deg[j] = 0;
}

// ---- build: bucket CSR fill, ushort slots (+1-shifted indices) -------------

__global__ void build(const int* __restrict__ src, const int* __restrict__ dst,
                      int* __restrict__ deg, unsigned short* __restrict__ csr) {
    int e = blockIdx.x * 256 + threadIdx.x;
    if (e < N_EDGES) {
        int d = dst[e];
        int slot = atomicAdd(&deg[d], 1);
        if (slot < BSTRIDE) csr[d * BSTRIDE + slot] = (unsigned short)(src[e] + 1);
    }
}

// ---- Linear+cube via split-bf16 MFMA: T[n+1] = cube(X @ W^T + B), bf16 -----
// ct-split for occupancy: block = (tile, ct-half); each wave owns ONE column
// tile (12 MFMAs, 8KB W) -> 25k waves instead of 3.1k.

__global__ __launch_bounds__(256) void linear_cube_mfma(const float* __restrict__ X,
                                                        const unsigned short* __restrict__ Whi,
                                                        const unsigned short* __restrict__ Wlo,
                                                        const float* __restrict__ B,
                                                        unsigned short* __restrict__ T) {
    int wave = threadIdx.x >> 6;
    int lane = threadIdx.x & 63;
    int tile = blockIdx.x >> 1;
    int ct = (blockIdx.x & 1) * 4 + wave;
    int n0 = tile * 16;
    int r = lane & 15;    // A-row (node) on load side; B/D column (output)
    int g = lane >> 4;    // k-group

    bf16x8 xh[4], xl[4];
    const float* xrow = X + (size_t)(n0 + r) * DIM + g * 8;
    #pragma unroll
    for (int kb = 0; kb < 4; kb++) {
        float4 a = *(const float4*)(xrow + kb * 32);
        float4 b = *(const float4*)(xrow + kb * 32 + 4);
        float v[8] = {a.x, a.y, a.z, a.w, b.x, b.y, b.z, b.w};
        #pragma unroll
        for (int j = 0; j < 8; j++) {
            unsigned short h = f2bf(v[j]);
            float rem = v[j] - bf2f(h);
            xh[kb][j] = (short)h;
            xl[kb][j] = (short)f2bf(rem);
        }
    }

    const unsigned short* whbase = Whi + (size_t)(ct * 16 + r) * DIM + g * 8;
    const unsigned short* wlbase = Wlo + (size_t)(ct * 16 + r) * DIM + g * 8;
    f32x4 acc = {0.f, 0.f, 0.f, 0.f};
    #pragma unroll
    for (int kb = 0; kb < 4; kb++) {
        bf16x8 wh = *(const bf16x8*)(whbase + kb * 32);
        bf16x8 wl = *(const bf16x8*)(wlbase + kb * 32);
        acc = __builtin_amdgcn_mfma_f32_16x16x32_bf16(xh[kb], wh, acc, 0, 0, 0);
        acc = __builtin_amdgcn_mfma_f32_16x16x32_bf16(xl[kb], wh, acc, 0, 0, 0);
        acc = __builtin_amdgcn_mfma_f32_16x16x32_bf16(xh[kb], wl, acc, 0, 0, 0);
    }
    float bias = B[ct * 16 + r];
    #pragma unroll
    for (int q = 0; q < 4; q++) {
        int node = g * 4 + q;   // D row = (lane>>4)*4 + reg  [m89]
        float h = acc[q] + bias;
        T[(size_t)(n0 + node + 1) * DIM + ct * 16 + r] = f2bf(cube_signed(h));
    }
}

// ---- Fused: aggregate(layer1)+ReLU -> split -> LDS bf16 planes -> MFMA -----
// R10-proven: 512 threads / 8 waves per 16-node tile; 2 nodes per wave.

__global__ __launch_bounds__(512) void agg_linear_cube(const unsigned* __restrict__ T32,
                                                       const int* __restrict__ deg,
                                                       const unsigned short* __restrict__ csr,
                                                       const unsigned short* __restrict__ Whi,
                                                       const unsigned short* __restrict__ Wlo,
                                                       const float* __restrict__ B,
                                                       unsigned short* __restrict__ Tout) {
    __shared__ __attribute__((aligned(16))) unsigned Phi[16][68];
    __shared__ __attribute__((aligned(16))) unsigned Plo[16][68];
    int wave = threadIdx.x >> 6;
    int lane = threadIdx.x & 63;
    int n0 = blockIdx.x * 16;
    int sub = lane & 15, grp = lane >> 4;

    // phase 1: aggregate + cbrt + relu + hi/lo split (2 nodes per wave)
    #pragma unroll
    for (int q = 0; q < 2; q++) {
        int row = wave * 2 + q;
        int nd = n0 + row;
        int d = deg[nd];
        int cnt = d < BSTRIDE ? d : BSTRIDE;
        float2 acc[4];
        gather_acc8(T32, csr + (size_t)nd * BSTRIDE, cnt, lane, acc);
        float c = (float)(d > 1 ? d : 1);
        float m0 = acc_pick_x(acc, grp) / c;
        float m1 = acc_pick_y(acc, grp) / c;
        float r0 = fmaxf(sgn(m0) * cbrt_pos(fabsf(m0) + EPSV), 0.f);
        float r1 = fmaxf(sgn(m1) * cbrt_pos(fabsf(m1) + EPSV), 0.f);
        unsigned short h0 = f2bf(r0), h1 = f2bf(r1);
        unsigned short l0 = f2bf(r0 - bf2f(h0)), l1 = f2bf(r1 - bf2f(h1));
        Phi[row][sub * 4 + grp] = (unsigned)h0 | ((unsigned)h1 << 16);
        Plo[row][sub * 4 + grp] = (unsigned)l0 | ((unsigned)l1 << 16);
    }
    __syncthreads();

    // phase 2: fragments straight from LDS planes
    int r = lane & 15;
    int g = lane >> 4;
    bf16x8 xh[4], xl[4];
    #pragma unroll
    for (int kb = 0; kb < 4; kb++) {
        xh[kb] = *(const bf16x8*)&Phi[r][kb * 16 + g * 4];
        xl[kb] = *(const bf16x8*)&Plo[r][kb * 16 + g * 4];
    }
    int ct = wave;
    const unsigned short* whbase = Whi + (size_t)(ct * 16 + r) * DIM + g * 8;
    const unsigned short* wlbase = Wlo + (size_t)(ct * 16 + r) * DIM + g * 8;
    f32x4 acc = {0.f, 0.f, 0.f, 0.f};
    #pragma unroll
    for (int kb = 0; kb < 4; kb++) {
        bf16x8 wh = *(const bf16x8*)(whbase + kb * 32);
        bf16x8 wl = *(const bf16x8*)(wlbase + kb * 32);
        acc = __builtin_amdgcn_mfma_f32_16x16x32_bf16(xh[kb], wh, acc, 0, 0, 0);
        acc = __builtin_amdgcn_mfma_f32_16x16x32_bf16(xl[kb], wh, acc, 0, 0, 0);
        acc = __builtin_amdgcn_mfma_f32_16x16x32_bf16(xh[kb], wl, acc, 0, 0, 0);
    }
    float bias = B[ct * 16 + r];
    #pragma unroll
    for (int q = 0; q < 4; q++) {
        int node = g * 4 + q;
        float h = acc[q] + bias;
        Tout[(size_t)(n0 + node + 1) * DIM + ct * 16 + r] = f2bf(cube_signed(h));
    }
}

// ---- Conv aggregate (layer 2): mean of bf16 cubes -> signed cbrt -> P fp32 -

__global__ __launch_bounds__(256) void aggregate(const unsigned* __restrict__ T32,
                                                 const int* __restrict__ deg,
                                                 const unsigned short* __restrict__ csr,
                                                 float* __restrict__ P) {
    int nd = blockIdx.x * 4 + (threadIdx.x >> 6);
    if (nd >= N_NODES) return;
    int lane = threadIdx.x & 63;
    int sub = lane & 15, grp = lane >> 4;
    int d = deg[nd];
    int cnt = d < BSTRIDE ? d : BSTRIDE;
    float2 acc[4];
    gather_acc8(T32, csr + (size_t)nd * BSTRIDE, cnt, lane, acc);
    float c = (float)(d > 1 ? d : 1);
    float m0 = acc_pick_x(acc, grp) / c;
    float m1 = acc_pick_y(acc, grp) / c;
    float r0 = sgn(m0) * cbrt_pos(fabsf(m0) + EPSV);
    float r1 = sgn(m1) * cbrt_pos(fabsf(m1) + EPSV);
    *(float2*)(P + (size_t)nd * DIM + sub * 8 + grp * 2) = make_float2(r0, r1);
}

// ---- Fused graph pool + final linear ---------------------------------------

__global__ __launch_bounds__(128) void pool_final(const float* __restrict__ P,
                                                  const int* __restrict__ gstart,
                                                  const float* __restrict__ Wout,
                                                  const float* __restrict__ bout,
                                                  float* __restrict__ out) {
    __shared__ float R[DIM];
    __shared__ float partial[128];
    int g = blockIdx.x, f = threadIdx.x;
    int s = gstart[g], e = gstart[g + 1];
    float acc = 0.f;
    for (int i = s; i < e; i++) {
        float v = P[(size_t)i * DIM + f];
        float m = fabsf(v) + EPSV;
        acc += sgn(v) * m * m;
    }
    int cnt = e - s;
    float c = (float)(cnt > 1 ? cnt : 1);
    float mean = acc / c;
    R[f] = sgn(mean) * sqrtf(fabsf(mean) + EPSV);
    __syncthreads();

    int o = f & 63;
    int half = f >> 6;
    const float4* W4 = (const float4*)Wout + o * 32 + half * 16;
    const float4* R4 = (const float4*)R + half * 16;
    float a = 0.f;
    #pragma unroll
    for (int k = 0; k < 16; k++) {
        float4 w = W4[k];
        float4 r = R4[k];
        a += r.x * w.x + r.y * w.y + r.z * w.z + r.w * w.w;
    }
    partial[f] = a;
    __syncthreads();
    if (f < OUTD) out[(size_t)g * OUTD + f] = bout[f] + partial[f] + partial[f + 64];
}

// ---- launch ----------------------------------------------------------------

extern "C" void kernel_launch(void* const* d_in, const int* in_sizes, int n_in,
                              void* d_out, int out_size, void* d_ws, size_t ws_size,
                              hipStream_t stream) {
    const float* x    = (const float*)d_in[0];
    const float* W1   = (const float*)d_in[1];
    const float* b1   = (const float*)d_in[2];
    const float* W2   = (const float*)d_in[3];
    const float* b2   = (const float*)d_in[4];
    const float* Wout = (const float*)d_in[5];
    const float* bout = (const float*)d_in[6];
    const int* edge   = (const int*)d_in[7];
    const int* batch  = (const int*)d_in[8];
    const int* srcp = edge;
    const int* dstp = edge + N_EDGES;
    float* out = (float*)d_out;

    char* ws = (char*)d_ws;
    size_t off = 0;
    auto alloc = [&](size_t bytes) -> char* {
        char* p = ws + off;
        off += (bytes + 255) / 256 * 256;
        return p;
    };
    unsigned short* T1 = (unsigned short*)alloc((size_t)(N_NODES + 1) * DIM * 2);
    unsigned short* T2 = (unsigned short*)alloc((size_t)(N_NODES + 1) * DIM * 2);
    float* P        = (float*)alloc((size_t)N_NODES * DIM * 4);
    int*   deg      = (int*)alloc((size_t)N_NODES * 4);
    unsigned short* csr = (unsigned short*)alloc((size_t)N_NODES * BSTRIDE * 2);
    int*   gstart   = (int*)alloc((size_t)(N_GRAPHS + 1) * 4);
    unsigned short* W1hi = (unsigned short*)alloc((size_t)DIM * DIM * 2);
    unsigned short* W1lo = (unsigned short*)alloc((size_t)DIM * DIM * 2);
    unsigned short* W2hi = (unsigned short*)alloc((size_t)DIM * DIM * 2);
    unsigned short* W2lo = (unsigned short*)alloc((size_t)DIM * DIM * 2);

    prep<<<64, 256, 0, stream>>>(W1, W2, W1hi, W1lo, W2hi, W2lo,
                                 deg, batch, gstart,
                                 (unsigned*)T1, (unsigned*)T2);
    build<<<EBLK, 256, 0, stream>>>(srcp, dstp, deg, csr);

    const int TILES = N_NODES / 16;           // 3125
    const int ABLK = (N_NODES + 3) / 4;       // 12500 blocks x 4 waves
    linear_cube_mfma<<<TILES * 2, 256, 0, stream>>>(x, W1hi, W1lo, b1, T1);
    agg_linear_cube<<<TILES, 512, 0, stream>>>((const unsigned*)T1, deg, csr,
                                               W2hi, W2lo, b2, T2);
    aggregate<<<ABLK, 256, 0, stream>>>((const unsigned*)T2, deg, csr, P);
    pool_final<<<N_GRAPHS, 128, 0, stream>>>(P, gstart, Wout, bout, out);
}

// Round 16
// 183.649 us; speedup vs baseline: 1.0689x; 1.0689x over previous
//
#include <hip/hip_runtime.h>
#include <hip/hip_bf16.h>
#include <math.h>

#define N_NODES 50000
#define N_EDGES 600000
#define N_GRAPHS 512
#define DIM 128
#define OUTD 64
#define EPSV 1e-6f
#define BSTRIDE 64     // bucket slots per node; mean deg 12, P(deg>64) ~ 0
#define EBLK4 586      // ceil(150000 quads / 256)
#define PREP_BLK 64    // 16384 threads = DIM*DIM

typedef __attribute__((ext_vector_type(8))) short bf16x8;
typedef __attribute__((ext_vector_type(4))) float f32x4;

__device__ __forceinline__ float sgn(float v) {
    return (v > 0.f) ? 1.f : ((v < 0.f) ? -1.f : 0.f);
}

__device__ __forceinline__ float cube_signed(float v) {
    float m = fabsf(v) + EPSV;
    return sgn(v) * m * m * m;
}

__device__ __forceinline__ float cbrt_pos(float m) {
    return exp2f(log2f(m) * (1.0f / 3.0f));
}

__device__ __forceinline__ unsigned short f2bf(float f) {
    unsigned u = __float_as_uint(f);
    unsigned r = (u + 0x7fff + ((u >> 16) & 1)) >> 16;   // RNE
    return (unsigned short)r;
}

__device__ __forceinline__ float bf2f(unsigned short h) {
    return __uint_as_float(((unsigned)h) << 16);
}

// Wide gather (R10-proven): lane&15 = feature octet, lane>>4 = edge slot.
// One uint4 load = 4 edges x 256B. Out-of-range slots masked ONCE at bucket
// load (idx 0 = dummy zero row of T) -> no csr memset needed.
__device__ __forceinline__ void gather_acc8(const unsigned* __restrict__ T32,
                                            const unsigned short* __restrict__ bucket,
                                            int cnt, int lane, float2 acc[4]) {
    #pragma unroll
    for (int j = 0; j < 4; j++) acc[j] = make_float2(0.f, 0.f);
    if (cnt <= 0) return;
    int myidx = (lane < cnt) ? (int)bucket[lane] : 0;   // coalesced 128B
    int sub = lane & 15, grp = lane >> 4;
    int cnt16 = (cnt + 15) & ~15;
    for (int i = 0; i < cnt16; i += 16) {
        uint4 u[4];
        #pragma unroll
        for (int c = 0; c < 4; c++) {
            int s = __shfl(myidx, i + c * 4 + grp, 64);
            u[c] = *(const uint4*)(T32 + (size_t)s * 64 + sub * 4);
        }
        #pragma unroll
        for (int c = 0; c < 4; c++) {
            acc[0].x += __uint_as_float(u[c].x << 16);
            acc[0].y += __uint_as_float(u[c].x & 0xffff0000u);
            acc[1].x += __uint_as_float(u[c].y << 16);
            acc[1].y += __uint_as_float(u[c].y & 0xffff0000u);
            acc[2].x += __uint_as_float(u[c].z << 16);
            acc[2].y += __uint_as_float(u[c].z & 0xffff0000u);
            acc[3].x += __uint_as_float(u[c].w << 16);
            acc[3].y += __uint_as_float(u[c].w & 0xffff0000u);
        }
    }
    #pragma unroll
    for (int j = 0; j < 4; j++) {
        acc[j].x += __shfl_xor(acc[j].x, 16, 64);
        acc[j].y += __shfl_xor(acc[j].y, 16, 64);
        acc[j].x += __shfl_xor(acc[j].x, 32, 64);
        acc[j].y += __shfl_xor(acc[j].y, 32, 64);
    }
}

__device__ __forceinline__ float acc_pick_x(const float2 acc[4], int grp) {
    return grp == 0 ? acc[0].x : grp == 1 ? acc[1].x : grp == 2 ? acc[2].x : acc[3].x;
}
__device__ __forceinline__ float acc_pick_y(const float2 acc[4], int grp) {
    return grp == 0 ? acc[0].y : grp == 1 ? acc[1].y : grp == 2 ? acc[2].y : acc[3].y;
}

// ---- buildprep: 4-edge/thread bucket fill || W split + gstart + T zero -----
// deg must be zeroed (memsetAsync) before this kernel.
// blocks [0,EBLK4): edges (uint4 reads, 4 independent chains);
// blocks [EBLK4, EBLK4+PREP_BLK): W1/W2 hi-lo split, gstart, T dummy rows.

__global__ void buildprep(const int* __restrict__ src, const int* __restrict__ dst,
                          int* __restrict__ deg, unsigned short* __restrict__ csr,
                          const float* __restrict__ W1, const float* __restrict__ W2,
                          unsigned short* __restrict__ W1hi, unsigned short* __restrict__ W1lo,
                          unsigned short* __restrict__ W2hi, unsigned short* __restrict__ W2lo,
                          const int* __restrict__ batch, int* __restrict__ gstart,
                          unsigned* __restrict__ T1z, unsigned* __restrict__ T2z) {
    int b = blockIdx.x;
    if (b < EBLK4) {
        int e4 = b * 256 + threadIdx.x;
        if (e4 < N_EDGES / 4) {
            uint4 s4 = ((const uint4*)src)[e4];
            uint4 d4 = ((const uint4*)dst)[e4];
            int d0 = (int)d4.x, d1 = (int)d4.y, d2 = (int)d4.z, d3 = (int)d4.w;
            int sl0 = atomicAdd(&deg[d0], 1);
            int sl1 = atomicAdd(&deg[d1], 1);
            int sl2 = atomicAdd(&deg[d2], 1);
            int sl3 = atomicAdd(&deg[d3], 1);
            if (sl0 < BSTRIDE) csr[d0 * BSTRIDE + sl0] = (unsigned short)(s4.x + 1);
            if (sl1 < BSTRIDE) csr[d1 * BSTRIDE + sl1] = (unsigned short)(s4.y + 1);
            if (sl2 < BSTRIDE) csr[d2 * BSTRIDE + sl2] = (unsigned short)(s4.z + 1);
            if (sl3 < BSTRIDE) csr[d3 * BSTRIDE + sl3] = (unsigned short)(s4.w + 1);
        }
        return;
    }
    int i = (b - EBLK4) * 256 + threadIdx.x;
    {
        float w = W1[i];
        unsigned short h = f2bf(w);
        W1hi[i] = h;
        W1lo[i] = f2bf(w - bf2f(h));
        w = W2[i];
        h = f2bf(w);
        W2hi[i] = h;
        W2lo[i] = f2bf(w - bf2f(h));
    }
    if (i < 64) { T1z[i] = 0u; T2z[i] = 0u; }   // dummy zero row 0
    if (i <= N_GRAPHS) {
        int lo = 0, hi = N_NODES;
        while (lo < hi) {
            int mid = (lo + hi) >> 1;
            if (batch[mid] < i) lo = mid + 1; else hi = mid;
        }
        gstart[i] = lo;
    }
}

// ---- Linear+cube via split-bf16 MFMA: T[n+1] = cube(X @ W^T + B), bf16 -----
// R14 shape (wave owns 16-node tile, 8 ct serial) + LDS-staged coalesced
// stores: bf16 results land in a private 4KB LDS region, then copied out as
// 4 x dwordx4 per lane (tile is 4KB contiguous in T).

__global__ __launch_bounds__(256) void linear_cube_mfma(const float* __restrict__ X,
                                                        const unsigned short* __restrict__ Whi,
                                                        const unsigned short* __restrict__ Wlo,
                                                        const float* __restrict__ B,
                                                        unsigned short* __restrict__ T) {
    __shared__ unsigned short Tl[4][16][DIM];
    int wave = threadIdx.x >> 6;
    int lane = threadIdx.x & 63;
    int tile = blockIdx.x * 4 + wave;
    if (tile >= N_NODES / 16) return;
    int n0 = tile * 16;
    int r = lane & 15;    // A-row (node) on load side; B/D column (output)
    int g = lane >> 4;    // k-group

    bf16x8 xh[4], xl[4];
    const float* xrow = X + (size_t)(n0 + r) * DIM + g * 8;
    #pragma unroll
    for (int kb = 0; kb < 4; kb++) {
        float4 a = *(const float4*)(xrow + kb * 32);
        float4 b = *(const float4*)(xrow + kb * 32 + 4);
        float v[8] = {a.x, a.y, a.z, a.w, b.x, b.y, b.z, b.w};
        #pragma unroll
        for (int j = 0; j < 8; j++) {
            unsigned short h = f2bf(v[j]);
            float rem = v[j] - bf2f(h);
            xh[kb][j] = (short)h;
            xl[kb][j] = (short)f2bf(rem);
        }
    }

    #pragma unroll
    for (int ct = 0; ct < 8; ct++) {
        const unsigned short* whbase = Whi + (size_t)(ct * 16 + r) * DIM + g * 8;
        const unsigned short* wlbase = Wlo + (size_t)(ct * 16 + r) * DIM + g * 8;
        f32x4 acc = {0.f, 0.f, 0.f, 0.f};
        #pragma unroll
        for (int kb = 0; kb < 4; kb++) {
            bf16x8 wh = *(const bf16x8*)(whbase + kb * 32);
            bf16x8 wl = *(const bf16x8*)(wlbase + kb * 32);
            acc = __builtin_amdgcn_mfma_f32_16x16x32_bf16(xh[kb], wh, acc, 0, 0, 0);
            acc = __builtin_amdgcn_mfma_f32_16x16x32_bf16(xl[kb], wh, acc, 0, 0, 0);
            acc = __builtin_amdgcn_mfma_f32_16x16x32_bf16(xh[kb], wl, acc, 0, 0, 0);
        }
        float bias = B[ct * 16 + r];
        #pragma unroll
        for (int q = 0; q < 4; q++) {
            int node = g * 4 + q;   // D row = (lane>>4)*4 + reg  [m89]
            float h = acc[q] + bias;
            Tl[wave][node][ct * 16 + r] = f2bf(cube_signed(h));
        }
    }

    // coalesced copy-out: 4KB contiguous tile
    uint4* dstg = (uint4*)(T + (size_t)(n0 + 1) * DIM);
    const uint4* srcl = (const uint4*)&Tl[wave][0][0];
    #pragma unroll
    for (int i = 0; i < 4; i++) {
        dstg[i * 64 + lane] = srcl[i * 64 + lane];
    }
}

// ---- Fused: aggregate(layer1)+ReLU -> split -> LDS bf16 planes -> MFMA -----
// R10-proven: 512 threads / 8 waves per 16-node tile; 2 nodes per wave.

__global__ __launch_bounds__(512) void agg_linear_cube(const unsigned* __restrict__ T32,
                                                       const int* __restrict__ deg,
                                                       const unsigned short* __restrict__ csr,
                                                       const unsigned short* __restrict__ Whi,
                                                       const unsigned short* __restrict__ Wlo,
                                                       const float* __restrict__ B,
                                                       unsigned short* __restrict__ Tout) {
    __shared__ __attribute__((aligned(16))) unsigned Phi[16][68];
    __shared__ __attribute__((aligned(16))) unsigned Plo[16][68];
    int wave = threadIdx.x >> 6;
    int lane = threadIdx.x & 63;
    int n0 = blockIdx.x * 16;
    int sub = lane & 15, grp = lane >> 4;

    // phase 1: aggregate + cbrt + relu + hi/lo split (2 nodes per wave)
    #pragma unroll
    for (int q = 0; q < 2; q++) {
        int row = wave * 2 + q;
        int nd = n0 + row;
        int d = deg[nd];
        int cnt = d < BSTRIDE ? d : BSTRIDE;
        float2 acc[4];
        gather_acc8(T32, csr + (size_t)nd * BSTRIDE, cnt, lane, acc);
        float c = (float)(d > 1 ? d : 1);
        float m0 = acc_pick_x(acc, grp) / c;
        float m1 = acc_pick_y(acc, grp) / c;
        float r0 = fmaxf(sgn(m0) * cbrt_pos(fabsf(m0) + EPSV), 0.f);
        float r1 = fmaxf(sgn(m1) * cbrt_pos(fabsf(m1) + EPSV), 0.f);
        unsigned short h0 = f2bf(r0), h1 = f2bf(r1);
        unsigned short l0 = f2bf(r0 - bf2f(h0)), l1 = f2bf(r1 - bf2f(h1));
        Phi[row][sub * 4 + grp] = (unsigned)h0 | ((unsigned)h1 << 16);
        Plo[row][sub * 4 + grp] = (unsigned)l0 | ((unsigned)l1 << 16);
    }
    __syncthreads();

    // phase 2: fragments straight from LDS planes
    int r = lane & 15;
    int g = lane >> 4;
    bf16x8 xh[4], xl[4];
    #pragma unroll
    for (int kb = 0; kb < 4; kb++) {
        xh[kb] = *(const bf16x8*)&Phi[r][kb * 16 + g * 4];
        xl[kb] = *(const bf16x8*)&Plo[r][kb * 16 + g * 4];
    }
    int ct = wave;
    const unsigned short* whbase = Whi + (size_t)(ct * 16 + r) * DIM + g * 8;
    const unsigned short* wlbase = Wlo + (size_t)(ct * 16 + r) * DIM + g * 8;
    f32x4 acc = {0.f, 0.f, 0.f, 0.f};
    #pragma unroll
    for (int kb = 0; kb < 4; kb++) {
        bf16x8 wh = *(const bf16x8*)(whbase + kb * 32);
        bf16x8 wl = *(const bf16x8*)(wlbase + kb * 32);
        acc = __builtin_amdgcn_mfma_f32_16x16x32_bf16(xh[kb], wh, acc, 0, 0, 0);
        acc = __builtin_amdgcn_mfma_f32_16x16x32_bf16(xl[kb], wh, acc, 0, 0, 0);
        acc = __builtin_amdgcn_mfma_f32_16x16x32_bf16(xh[kb], wl, acc, 0, 0, 0);
    }
    float bias = B[ct * 16 + r];
    #pragma unroll
    for (int q = 0; q < 4; q++) {
        int node = g * 4 + q;
        float h = acc[q] + bias;
        Tout[(size_t)(n0 + node + 1) * DIM + ct * 16 + r] = f2bf(cube_signed(h));
    }
}

// ---- Conv aggregate (layer 2): mean of bf16 cubes -> signed cbrt -> P fp32 -

__global__ __launch_bounds__(256) void aggregate(const unsigned* __restrict__ T32,
                                                 const int* __restrict__ deg,
                                                 const unsigned short* __restrict__ csr,
                                                 float* __restrict__ P) {
    int nd = blockIdx.x * 4 + (threadIdx.x >> 6);
    if (nd >= N_NODES) return;
    int lane = threadIdx.x & 63;
    int sub = lane & 15, grp = lane >> 4;
    int d = deg[nd];
    int cnt = d < BSTRIDE ? d : BSTRIDE;
    float2 acc[4];
    gather_acc8(T32, csr + (size_t)nd * BSTRIDE, cnt, lane, acc);
    float c = (float)(d > 1 ? d : 1);
    float m0 = acc_pick_x(acc, grp) / c;
    float m1 = acc_pick_y(acc, grp) / c;
    float r0 = sgn(m0) * cbrt_pos(fabsf(m0) + EPSV);
    float r1 = sgn(m1) * cbrt_pos(fabsf(m1) + EPSV);
    *(float2*)(P + (size_t)nd * DIM + sub * 8 + grp * 2) = make_float2(r0, r1);
}

// ---- Fused graph pool + final linear ---------------------------------------

__global__ __launch_bounds__(128) void pool_final(const float* __restrict__ P,
                                                  const int* __restrict__ gstart,
                                                  const float* __restrict__ Wout,
                                                  const float* __restrict__ bout,
                                                  float* __restrict__ out) {
    __shared__ float R[DIM];
    __shared__ float partial[128];
    int g = blockIdx.x, f = threadIdx.x;
    int s = gstart[g], e = gstart[g + 1];
    float acc = 0.f;
    for (int i = s; i < e; i++) {
        float v = P[(size_t)i * DIM + f];
        float m = fabsf(v) + EPSV;
        acc += sgn(v) * m * m;
    }
    int cnt = e - s;
    float c = (float)(cnt > 1 ? cnt : 1);
    float mean = acc / c;
    R[f] = sgn(mean) * sqrtf(fabsf(mean) + EPSV);
    __syncthreads();

    int o = f & 63;
    int half = f >> 6;
    const float4* W4 = (const float4*)Wout + o * 32 + half * 16;
    const float4* R4 = (const float4*)R + half * 16;
    float a = 0.f;
    #pragma unroll
    for (int k = 0; k < 16; k++) {
        float4 w = W4[k];
        float4 r = R4[k];
        a += r.x * w.x + r.y * w.y + r.z * w.z + r.w * w.w;
    }
    partial[f] = a;
    __syncthreads();
    if (f < OUTD) out[(size_t)g * OUTD + f] = bout[f] + partial[f] + partial[f + 64];
}

// ---- launch ----------------------------------------------------------------

extern "C" void kernel_launch(void* const* d_in, const int* in_sizes, int n_in,
                              void* d_out, int out_size, void* d_ws, size_t ws_size,
                              hipStream_t stream) {
    const float* x    = (const float*)d_in[0];
    const float* W1   = (const float*)d_in[1];
    const float* b1   = (const float*)d_in[2];
    const float* W2   = (const float*)d_in[3];
    const float* b2   = (const float*)d_in[4];
    const float* Wout = (const float*)d_in[5];
    const float* bout = (const float*)d_in[6];
    const int* edge   = (const int*)d_in[7];
    const int* batch  = (const int*)d_in[8];
    const int* srcp = edge;
    const int* dstp = edge + N_EDGES;
    float* out = (float*)d_out;

    char* ws = (char*)d_ws;
    size_t off = 0;
    auto alloc = [&](size_t bytes) -> char* {
        char* p = ws + off;
        off += (bytes + 255) / 256 * 256;
        return p;
    };
    unsigned short* T1 = (unsigned short*)alloc((size_t)(N_NODES + 1) * DIM * 2);
    unsigned short* T2 = (unsigned short*)alloc((size_t)(N_NODES + 1) * DIM * 2);
    float* P        = (float*)alloc((size_t)N_NODES * DIM * 4);
    int*   deg      = (int*)alloc((size_t)N_NODES * 4);
    unsigned short* csr = (unsigned short*)alloc((size_t)N_NODES * BSTRIDE * 2);
    int*   gstart   = (int*)alloc((size_t)(N_GRAPHS + 1) * 4);
    unsigned short* W1hi = (unsigned short*)alloc((size_t)DIM * DIM * 2);
    unsigned short* W1lo = (unsigned short*)alloc((size_t)DIM * DIM * 2);
    unsigned short* W2hi = (unsigned short*)alloc((size_t)DIM * DIM * 2);
    unsigned short* W2lo = (unsigned short*)alloc((size_t)DIM * DIM * 2);

    hipMemsetAsync(deg, 0, (size_t)N_NODES * 4, stream);
    buildprep<<<EBLK4 + PREP_BLK, 256, 0, stream>>>(srcp, dstp, deg, csr,
                                                    W1, W2, W1hi, W1lo, W2hi, W2lo,
                                                    batch, gstart,
                                                    (unsigned*)T1, (unsigned*)T2);

    const int TILES = N_NODES / 16;           // 3125
    const int LBLK = (TILES + 3) / 4;         // 782 blocks x 4 waves
    const int ABLK = (N_NODES + 3) / 4;       // 12500 blocks x 4 waves
    linear_cube_mfma<<<LBLK, 256, 0, stream>>>(x, W1hi, W1lo, b1, T1);
    agg_linear_cube<<<TILES, 512, 0, stream>>>((const unsigned*)T1, deg, csr,
                                               W2hi, W2lo, b2, T2);
    aggregate<<<ABLK, 256, 0, stream>>>((const unsigned*)T2, deg, csr, P);
    pool_final<<<N_GRAPHS, 128, 0, stream>>>(P, gstart, Wout, bout, out);
}